// Round 10
// baseline (96.757 us; speedup 1.0000x reference)
//
#include <hip/hip_runtime.h>

// Problem constants
#define IH 4096
#define IW 4096
#define KH 11
#define KW 11
#define OH (IH - KH + 1)   // 4086
#define OW (IW - KW + 1)   // 4086

// Tiling
#define BM 64              // output tile rows per block
#define BN 64              // output tile cols per block
#define TM 4               // outputs per thread (rows)
#define TN 4               // outputs per thread (cols)
#define TX 16
#define TY 16
#define LDS_H (BM + KH - 1)        // 74 input rows
#define LDS_W 76                   // row stride: 74 data + 2 swizzle slack
#define NC    19                   // chunks/row: 18 float4 + 1 float2 (=74 floats)
#define NCHUNK (LDS_H * NC)        // 1406
#define NITER  6                   // staging iterations (256 threads)
#define TILE_FLOATS (LDS_H * LDS_W)  // 5624
#define TILES_X 64                 // 4096/64 output-tile grid
#define TILES_TOTAL 4096

// 8B-per-row swizzle (round 8, verified): rows 4 apart get distinct mod-4
// bank residues for the b64 word phases -> conflicts 5.07e7 -> 9.2e6.
#define OF(row) ((((row) >> 2) & 1) * 2)

// ---- staging split: issue loads early (T14), write LDS late ----
__device__ __forceinline__ void stage_load(float4 G[NITER], const float* __restrict__ x,
                                           int gx0, int gy0, int tid) {
#pragma unroll
    for (int it = 0; it < NITER; ++it) {
        const int i = tid + it * 256;
        float4 v = make_float4(0.f, 0.f, 0.f, 0.f);
        if (i < NCHUNK) {
            const int r  = i / NC;
            const int c4 = i - r * NC;
            const int gy = gy0 + r;
            const int gx = gx0 + c4 * 4;
            if (gy < IH && gx + 3 < IW) {
                v = *reinterpret_cast<const float4*>(x + (size_t)gy * IW + gx);
            }
        }
        G[it] = v;
    }
}

__device__ __forceinline__ void stage_write(float* __restrict__ tb,
                                            const float4 G[NITER], int tid) {
#pragma unroll
    for (int it = 0; it < NITER; ++it) {
        const int i = tid + it * 256;
        if (i < NCHUNK) {
            const int r  = i / NC;
            const int c4 = i - r * NC;
            float* dst = &tb[r * LDS_W + OF(r) + c4 * 4];   // 8B aligned
            *reinterpret_cast<float2*>(dst) = make_float2(G[it].x, G[it].y);
            if (c4 < NC - 1) {
                *reinterpret_cast<float2*>(dst + 2) = make_float2(G[it].z, G[it].w);
            }
        }
    }
}

// ---- per-tile compute: rolling 4-row register window + weight dbuf ----
__device__ __forceinline__ void compute_tile(const float* __restrict__ tb,
                                             const float* __restrict__ wp,
                                             float bv, float* __restrict__ out,
                                             int gx0, int gy0, int lx, int ly) {
    float acc[TM][TN] = {};
    float xv[4][14];
    // Weight-row double buffer: STEP(kh) CONSUMES wkb[kh&1] (loaded during the
    // previous step -> latency hidden) and ISSUES loads for row kh+1 into
    // wkb[(kh+1)&1]. No readfirstlane: rfl forced a wait at issue time, which
    // was the round-9 per-STEP ~200cy stall (VALUBusy pinned at ~48%).
    float wkb[2][KW];

#define LOADROW(S, RR) do {                                                  \
        const int row_ = ly + (RR);                                          \
        const float* src_ = &tb[row_ * LDS_W + OF(row_) + lx];               \
        float2 q0 = *reinterpret_cast<const float2*>(src_);                  \
        float2 q1 = *reinterpret_cast<const float2*>(src_ + 2);              \
        float2 q2 = *reinterpret_cast<const float2*>(src_ + 4);              \
        float2 q3 = *reinterpret_cast<const float2*>(src_ + 6);              \
        float2 q4 = *reinterpret_cast<const float2*>(src_ + 8);              \
        float2 q5 = *reinterpret_cast<const float2*>(src_ + 10);             \
        float2 q6 = *reinterpret_cast<const float2*>(src_ + 12);             \
        xv[(S)][0]=q0.x;  xv[(S)][1]=q0.y;  xv[(S)][2]=q1.x;  xv[(S)][3]=q1.y; \
        xv[(S)][4]=q2.x;  xv[(S)][5]=q2.y;  xv[(S)][6]=q3.x;  xv[(S)][7]=q3.y; \
        xv[(S)][8]=q4.x;  xv[(S)][9]=q4.y;  xv[(S)][10]=q5.x; xv[(S)][11]=q5.y; \
        xv[(S)][12]=q6.x; xv[(S)][13]=q6.y;                                  \
    } while (0)

#define STEP(U, KHV) do {                                                    \
        if ((KHV) + 1 < KH) {                                                \
            _Pragma("unroll")                                                \
            for (int kw = 0; kw < KW; ++kw)                                  \
                wkb[((U) + 1) & 1][kw] = wp[((KHV) + 1) * KW + kw];          \
        }                                                                    \
        LOADROW(((U) + 3) & 3, (KHV) + 3);                                   \
        _Pragma("unroll")                                                    \
        for (int ry = 0; ry < TM; ++ry) {                                    \
            const float* xr = xv[((U) + ry) & 3];                            \
            _Pragma("unroll")                                                \
            for (int kw = 0; kw < KW; ++kw) {                                \
                const float wv = wkb[(U) & 1][kw];                           \
                _Pragma("unroll")                                            \
                for (int rx = 0; rx < TN; ++rx) {                            \
                    acc[ry][rx] = fmaf(xr[kw + rx], wv, acc[ry][rx]);        \
                }                                                            \
            }                                                                \
        }                                                                    \
    } while (0)

    // Prologue: rows 0,1,2 into slots 0,1,2; weight row 0 into wkb[0].
    LOADROW(0, 0);
    LOADROW(1, 1);
    LOADROW(2, 2);
#pragma unroll
    for (int kw = 0; kw < KW; ++kw) wkb[0][kw] = wp[kw];

    // kh = 0..7: 2 runtime iterations of an unroll-4 body (bounds the
    // scheduler's live set — the rounds-0-5 lesson), then tail kh = 8,9,10.
#pragma unroll 1
    for (int t = 0; t < 2; ++t) {
        const int kh0 = 4 * t;
        STEP(0, kh0 + 0);
        STEP(1, kh0 + 1);
        STEP(2, kh0 + 2);
        STEP(3, kh0 + 3);
    }
    STEP(0, 8);
    STEP(1, 9);
    STEP(2, 10);

#undef STEP
#undef LOADROW

    // ---- Write back ----
    const int ox = gx0 + lx;
#pragma unroll
    for (int ry = 0; ry < TM; ++ry) {
        const int oy = gy0 + ly + ry;
        if (oy < OH) {
            const size_t base = (size_t)oy * OW + ox;
            if (ox + TN - 1 < OW) {
                float2 p0 = make_float2(acc[ry][0] + bv, acc[ry][1] + bv);
                float2 p1 = make_float2(acc[ry][2] + bv, acc[ry][3] + bv);
                *reinterpret_cast<float2*>(out + base)     = p0;
                *reinterpret_cast<float2*>(out + base + 2) = p1;
            } else {
#pragma unroll
                for (int rx = 0; rx < TN; ++rx) {
                    if (ox + rx < OW) out[base + rx] = acc[ry][rx] + bv;
                }
            }
        }
    }
}

// Persistent 2-tile blocks with LDS double-buffer: tile1's global loads are
// issued BEFORE tile0's compute (HBM latency hides under ~43k cy of FMA),
// LDS-written after, one barrier publishes. Halves the exposed staging.
__global__ __launch_bounds__(256)
void conv2d_f32_persist(const float* __restrict__ x,
                        const float* __restrict__ w,
                        const float* __restrict__ bias,
                        float* __restrict__ out) {
    __shared__ float buf[2][TILE_FLOATS];   // 2 x 22496 B = 44992 B -> 3 blk/CU

    const int tid = threadIdx.x;
    const int tx = tid & (TX - 1);
    const int ty = tid >> 4;
    const int lx = tx * TN;
    const int ly = ty * TM;
    const float bv = bias[0];

    // Two adjacent-x tiles per block (same tile row since id0 is even).
    const int id0 = blockIdx.x * 2;
    const int id1 = id0 + 1;
    const int gx0_0 = (id0 & (TILES_X - 1)) * BN, gy0_0 = (id0 >> 6) * BM;
    const int gx0_1 = (id1 & (TILES_X - 1)) * BN, gy0_1 = (id1 >> 6) * BM;

    // Stage tile 0 directly.
    {
        float4 G0[NITER];
        stage_load(G0, x, gx0_0, gy0_0, tid);
        stage_write(buf[0], G0, tid);
    }
    __syncthreads();

    // Issue tile 1's global loads now; consume after tile 0's compute.
    float4 G[NITER];
    stage_load(G, x, gx0_1, gy0_1, tid);
    // Keep the loads above the compute (don't let the scheduler sink them
    // to stage_write — that would kill the overlap).
    __builtin_amdgcn_sched_barrier(0);

    compute_tile(buf[0], w, bv, out, gx0_0, gy0_0, lx, ly);

    stage_write(buf[1], G, tid);
    __syncthreads();

    compute_tile(buf[1], w, bv, out, gx0_1, gy0_1, lx, ly);
}

extern "C" void kernel_launch(void* const* d_in, const int* in_sizes, int n_in,
                              void* d_out, int out_size, void* d_ws, size_t ws_size,
                              hipStream_t stream) {
    const float* x    = (const float*)d_in[0];
    const float* w    = (const float*)d_in[1];
    const float* bias = (const float*)d_in[2];
    float* out        = (float*)d_out;

    dim3 grid(TILES_TOTAL / 2);   // 2048 blocks x 2 tiles
    dim3 block(TX * TY);          // 256
    conv2d_f32_persist<<<grid, block, 0, stream>>>(x, w, bias, out);
}

// Round 11
// 46.114 us; speedup vs baseline: 2.0982x; 2.0982x over previous
//
#include <hip/hip_runtime.h>
#include <hip/hip_bf16.h>

// Problem constants
#define IH 4096
#define IW 4096
#define KH 11
#define KW 11
#define OH (IH - KH + 1)   // 4086
#define OW (IW - KW + 1)   // 4086

// Block tile: 64x64 outputs, 4 waves; wave w -> rows 16w..16w+15 (4 col-tiles)
#define BM 64
#define BN 64
#define TROWS   74          // staged input rows  (64 + 10 halo)
#define TCOLS   80          // staged input cols  (64 + 10 halo, padded to 80)
#define TSTRIDE 84          // LDS row stride in bf16: 42 words -> 10r mod 32
                            // hits all 16 even residues for 16 consecutive
                            // rows => A-reads ~2-way worst (b64 word phases)
#define NC4     20          // float4 chunks per staged row (80 floats)
#define NCHUNK  (TROWS * NC4)      // 1480
#define NITER   6                  // ceil(1480/256)
#define B_OFF   (TROWS * TSTRIDE)  // bf16 offset of B-matrix region (6216)
// B region: [KH][16][32] bf16 = 11*512 = 5632 shorts. Total LDS 23696 B.

typedef short bf16x4 __attribute__((ext_vector_type(4)));
typedef short bf16x8 __attribute__((ext_vector_type(8)));
typedef float f32x4  __attribute__((ext_vector_type(4)));

__device__ __forceinline__ short f2b(float f) {
    __hip_bfloat16 h = __float2bfloat16(f);   // RNE
    return __builtin_bit_cast(short, h);
}

// Banded-Toeplitz MFMA conv:
//   out[oy0+i][ox0+j] = sum_kh sum_k A_kh[i][k] * B_kh[k][j]
//   A_kh[i][k] = X[oy0+kh+i][ox0+k]   (16x32 slab of the staged tile)
//   B_kh[k][j] = w[kh][k-j] for 0<=k-j<11 else 0   (32x16 banded)
// k-order freedom: any k-permutation consistent between A and B cancels in
// the dot product, so only the documented row/col lane maps matter
// (A row = lane&15, B col = lane&15, C/D col=lane&15,row=(lane>>4)*4+reg).
__global__ __launch_bounds__(256)
void conv2d_mfma(const float* __restrict__ x,
                 const float* __restrict__ w,
                 const float* __restrict__ bias,
                 float* __restrict__ out) {
    __shared__ short lds[B_OFF + KH * 512];   // input tile (bf16) + B matrix

    const int tid = threadIdx.x;
    const int gx0 = blockIdx.x * BN;
    const int gy0 = blockIdx.y * BM;

    // ---- Stage 74x80 input tile as bf16 (global float4 -> ds_write_b64) ----
#pragma unroll
    for (int it = 0; it < NITER; ++it) {
        const int i = tid + it * 256;
        if (i < NCHUNK) {
            const int r  = i / NC4;
            const int c4 = i - r * NC4;
            const int gy = gy0 + r;
            const int gx = gx0 + c4 * 4;
            float4 v = make_float4(0.f, 0.f, 0.f, 0.f);
            if (gy < IH && gx + 3 < IW) {
                v = *reinterpret_cast<const float4*>(x + (size_t)gy * IW + gx);
            }
            bf16x4 b = { f2b(v.x), f2b(v.y), f2b(v.z), f2b(v.w) };
            *reinterpret_cast<bf16x4*>(&lds[r * TSTRIDE + c4 * 4]) = b;
        }
    }

    // ---- Build B matrices: layout [kh][j][k] (k contiguous for b128 frag) ----
#pragma unroll
    for (int t = 0; t < 22; ++t) {             // 22*256 = 5632 exact
        const int idx = tid + t * 256;
        const int kh = idx >> 9;
        const int j  = (idx >> 5) & 15;
        const int k  = idx & 31;
        const int d  = k - j;
        const float val = (d >= 0 && d < KW) ? w[kh * KW + d] : 0.f;
        lds[B_OFF + idx] = f2b(val);
    }
    __syncthreads();

    // ---- Compute: wave wv owns rows 16wv..16wv+15, 4 col-tiles ----
    const int lane = tid & 63;
    const int wv   = tid >> 6;
    const int g    = lane >> 4;     // 0..3
    const int li   = lane & 15;

    f32x4 acc[4] = {};              // one 16x16 tile per col-block c

    // A fragment: lane reads row (16wv+kh+li), cols 16c + 8g .. +7 (bf16).
    // Two ds_read_b64 (8B aligned; stride 84*2B=168 is not 16B-multiple,
    // which also stops the compiler merging into a misaligned b128).
    const short* ap = &lds[(16 * wv + li) * TSTRIDE + g * 8];
    const short* bp = &lds[B_OFF + li * 32 + g * 8];

    // Runtime kh loop (11 small iterations): bounds the scheduler's live set
    // — rounds 0-5 proved fully-unrolled big bodies balloon to 256 VGPR.
#pragma unroll 1
    for (int kh = 0; kh < KH; ++kh) {
        const bf16x8 bfrag = *reinterpret_cast<const bf16x8*>(bp + kh * 512);
#pragma unroll
        for (int c = 0; c < 4; ++c) {
            bf16x4 lo = *reinterpret_cast<const bf16x4*>(ap + c * 16);
            bf16x4 hi = *reinterpret_cast<const bf16x4*>(ap + c * 16 + 4);
            bf16x8 a  = __builtin_shufflevector(lo, hi, 0, 1, 2, 3, 4, 5, 6, 7);
            acc[c] = __builtin_amdgcn_mfma_f32_16x16x32_bf16(a, bfrag, acc[c],
                                                             0, 0, 0);
        }
        ap += TSTRIDE;   // next kh -> input row +1
    }

    // ---- Write back: C/D map col=lane&15, row=(lane>>4)*4+reg [m89] ----
    const float bv = bias[0];
#pragma unroll
    for (int c = 0; c < 4; ++c) {
        const int ox = gx0 + c * 16 + li;
        if (ox < OW) {
#pragma unroll
            for (int r = 0; r < 4; ++r) {
                const int oy = gy0 + wv * 16 + g * 4 + r;
                if (oy < OH) {
                    out[(size_t)oy * OW + ox] = acc[c][r] + bv;
                }
            }
        }
    }
}

extern "C" void kernel_launch(void* const* d_in, const int* in_sizes, int n_in,
                              void* d_out, int out_size, void* d_ws, size_t ws_size,
                              hipStream_t stream) {
    const float* x    = (const float*)d_in[0];
    const float* w    = (const float*)d_in[1];
    const float* bias = (const float*)d_in[2];
    float* out        = (float*)d_out;

    dim3 grid(64, 64);    // 4096 blocks of 64x64 outputs
    dim3 block(256);
    conv2d_mfma<<<grid, block, 0, stream>>>(x, w, bias, out);
}

// Round 12
// 42.755 us; speedup vs baseline: 2.2631x; 1.0786x over previous
//
#include <hip/hip_runtime.h>
#include <hip/hip_bf16.h>

// Problem constants
#define IH 4096
#define IW 4096
#define KH 11
#define KW 11
#define OH (IH - KH + 1)   // 4086
#define OW (IW - KW + 1)   // 4086

// Block tile: 64x64 outputs, 4 waves; wave wv -> rows 16wv..16wv+15
#define BM 64
#define BN 64
#define TROWS   74          // staged input rows (64 + 10 halo)
#define TSTRIDE 84          // LDS row stride in bf16 (proven low-conflict r11)
#define NC4     20          // float4 chunks per staged row (80 floats)
#define NCHUNK  (TROWS * NC4)      // 1480
#define NITER   6                  // ceil(1480/256)
#define B_OFF   (TROWS * TSTRIDE)  // 6216 shorts
// LDS: input tile (bf16) + B matrices [KH][16][32] = 6216 + 5632 shorts = 23696 B

#define TILES_X 64
#define NPAIR   2048        // 2 adjacent-x tiles per block

typedef short bf16x4 __attribute__((ext_vector_type(4)));
typedef short bf16x8 __attribute__((ext_vector_type(8)));
typedef float f32x4  __attribute__((ext_vector_type(4)));

__device__ __forceinline__ short f2b(float f) {
    __hip_bfloat16 h = __float2bfloat16(f);   // RNE
    return __builtin_bit_cast(short, h);
}

// ---- staging split (T14): issue global loads early, LDS-write late ----
__device__ __forceinline__ void stage_load(float4 G[NITER],
                                           const float* __restrict__ x,
                                           int gx0, int gy0, int tid) {
#pragma unroll
    for (int it = 0; it < NITER; ++it) {
        const int i = tid + it * 256;
        float4 v = make_float4(0.f, 0.f, 0.f, 0.f);
        if (i < NCHUNK) {
            const int r  = i / NC4;
            const int c4 = i - r * NC4;
            const int gy = gy0 + r;
            const int gx = gx0 + c4 * 4;
            if (gy < IH && gx + 3 < IW) {
                v = *reinterpret_cast<const float4*>(x + (size_t)gy * IW + gx);
            }
        }
        G[it] = v;
    }
}

__device__ __forceinline__ void stage_write(short* __restrict__ lds,
                                            const float4 G[NITER], int tid) {
#pragma unroll
    for (int it = 0; it < NITER; ++it) {
        const int i = tid + it * 256;
        if (i < NCHUNK) {
            const int r  = i / NC4;
            const int c4 = i - r * NC4;
            bf16x4 b = { f2b(G[it].x), f2b(G[it].y), f2b(G[it].z), f2b(G[it].w) };
            *reinterpret_cast<bf16x4*>(&lds[r * TSTRIDE + c4 * 4]) = b;
        }
    }
}

// ---- per-tile MFMA compute (verified round 11 — unchanged math) ----
// out[oy0+i][ox0+j] = sum_kh sum_k A_kh[i][k]*B_kh[k][j],
// A_kh[i][k] = X[oy0+kh+i][ox0+k], B_kh[k][j] = w[kh][k-j] (banded).
// Consistent k-permutations between A and B cancel; relies only on
// A row = lane&15, B col = lane&15, C/D col=lane&15,row=(lane>>4)*4+reg.
__device__ __forceinline__ void compute_tile(const short* __restrict__ lds,
                                             float bv, float* __restrict__ out,
                                             int gx0, int gy0,
                                             int wv, int g, int li) {
    f32x4 acc[4] = {};
    const short* ap = &lds[(16 * wv + li) * TSTRIDE + g * 8];
    const short* bp = &lds[B_OFF + li * 32 + g * 8];

#pragma unroll 1
    for (int kh = 0; kh < KH; ++kh) {
        const bf16x8 bfrag = *reinterpret_cast<const bf16x8*>(bp + kh * 512);
#pragma unroll
        for (int c = 0; c < 4; ++c) {
            bf16x4 lo = *reinterpret_cast<const bf16x4*>(ap + c * 16);
            bf16x4 hi = *reinterpret_cast<const bf16x4*>(ap + c * 16 + 4);
            bf16x8 a  = __builtin_shufflevector(lo, hi, 0, 1, 2, 3, 4, 5, 6, 7);
            acc[c] = __builtin_amdgcn_mfma_f32_16x16x32_bf16(a, bfrag, acc[c],
                                                             0, 0, 0);
        }
        ap += TSTRIDE;
    }

#pragma unroll
    for (int c = 0; c < 4; ++c) {
        const int ox = gx0 + c * 16 + li;
        if (ox < OW) {
#pragma unroll
            for (int r = 0; r < 4; ++r) {
                const int oy = gy0 + wv * 16 + g * 4 + r;
                if (oy < OH) {
                    out[(size_t)oy * OW + ox] = acc[c][r] + bv;
                }
            }
        }
    }
}

// Persistent 2-tile block: single bf16 tile buffer; tile1's global loads are
// issued BEFORE tile0's compute (T14) so HBM latency hides under MFMA; the
// ds_write + barrier after compute is the only exposed cost (~300 cyc).
// Round-10 lesson honored: LDS stays 23.7 KB (no occupancy loss).
__global__ __launch_bounds__(256)
void conv2d_mfma2(const float* __restrict__ x,
                  const float* __restrict__ w,
                  const float* __restrict__ bias,
                  float* __restrict__ out) {
    __shared__ short lds[B_OFF + KH * 512];

    const int tid = threadIdx.x;
    // XCD-bijective swizzle (2048 % 8 == 0): each XCD gets 256 contiguous
    // pairs = 8 full tile rows -> x/y halo re-reads hit the same L2.
    const int pair = (blockIdx.x & 7) * (NPAIR / 8) + (blockIdx.x >> 3);
    const int t0 = pair * 2;            // even -> t0,t0+1 share a tile row
    const int gy0   = (t0 >> 6) * BM;
    const int gx0_0 = (t0 & (TILES_X - 1)) * BN;
    const int gx0_1 = gx0_0 + BN;

    const int lane = tid & 63;
    const int wv   = tid >> 6;
    const int g    = lane >> 4;
    const int li   = lane & 15;
    const float bv = bias[0];

    // Stage tile 0 + build B (once per block, shared by both tiles).
    {
        float4 G0[NITER];
        stage_load(G0, x, gx0_0, gy0, tid);
        stage_write(lds, G0, tid);
    }
#pragma unroll
    for (int t = 0; t < 22; ++t) {             // 22*256 = 5632 exact
        const int idx = tid + t * 256;
        const int kh = idx >> 9;
        const int j  = (idx >> 5) & 15;
        const int k  = idx & 31;
        const int d  = k - j;
        const float val = (d >= 0 && d < KW) ? w[kh * KW + d] : 0.f;
        lds[B_OFF + idx] = f2b(val);
    }
    __syncthreads();

    // Issue tile 1's global loads now; consumed after tile 0's compute.
    float4 G[NITER];
    stage_load(G, x, gx0_1, gy0, tid);
    __builtin_amdgcn_sched_barrier(0);   // keep loads above the compute

    compute_tile(lds, bv, out, gx0_0, gy0, wv, g, li);

    __syncthreads();                     // all reads of tile 0 done
    stage_write(lds, G, tid);
    __syncthreads();                     // publish tile 1

    compute_tile(lds, bv, out, gx0_1, gy0, wv, g, li);
}

extern "C" void kernel_launch(void* const* d_in, const int* in_sizes, int n_in,
                              void* d_out, int out_size, void* d_ws, size_t ws_size,
                              hipStream_t stream) {
    const float* x    = (const float*)d_in[0];
    const float* w    = (const float*)d_in[1];
    const float* bias = (const float*)d_in[2];
    float* out        = (float*)d_out;

    dim3 grid(NPAIR);     // 2048 blocks x 2 tiles
    dim3 block(256);
    conv2d_mfma2<<<grid, block, 0, stream>>>(x, w, bias, out);
}

// Round 13
// 40.944 us; speedup vs baseline: 2.3631x; 1.0442x over previous
//
#include <hip/hip_runtime.h>
#include <hip/hip_bf16.h>

// Problem constants
#define IH 4096
#define IW 4096
#define KH 11
#define KW 11
#define OH (IH - KH + 1)   // 4086
#define OW (IW - KW + 1)   // 4086

// Block tile: 64x64 outputs, 4 waves; wave wv -> rows 16wv..16wv+15
#define BM 64
#define BN 64
#define TROWS   74          // staged input rows (64 + 10 halo)
#define TSTRIDE 84          // LDS row stride in bf16 (proven low-conflict r11/r12)
#define NC4     20          // float4 chunks per staged row (80 floats)
#define NCHUNK  (TROWS * NC4)      // 1480
#define NITER   6                  // ceil(1480/256)
#define TILE_SHORTS (TROWS * TSTRIDE)  // 6216

#define TILES_X 64
#define NBLK    1024        // 4 adjacent-x tiles per block

typedef short bf16x4 __attribute__((ext_vector_type(4)));
typedef short bf16x8 __attribute__((ext_vector_type(8)));
typedef float f32x4  __attribute__((ext_vector_type(4)));

__device__ __forceinline__ short f2b(float f) {
    __hip_bfloat16 h = __float2bfloat16(f);   // RNE
    return __builtin_bit_cast(short, h);
}

// ---- staging split (T14): issue global loads early, LDS-write late ----
__device__ __forceinline__ void stage_load(float4 G[NITER],
                                           const float* __restrict__ x,
                                           int gx0, int gy0, int tid) {
#pragma unroll
    for (int it = 0; it < NITER; ++it) {
        const int i = tid + it * 256;
        float4 v = make_float4(0.f, 0.f, 0.f, 0.f);
        if (i < NCHUNK) {
            const int r  = i / NC4;
            const int c4 = i - r * NC4;
            const int gy = gy0 + r;
            const int gx = gx0 + c4 * 4;
            if (gy < IH && gx + 3 < IW) {
                v = *reinterpret_cast<const float4*>(x + (size_t)gy * IW + gx);
            }
        }
        G[it] = v;
    }
}

__device__ __forceinline__ void stage_write(short* __restrict__ tb,
                                            const float4 G[NITER], int tid) {
#pragma unroll
    for (int it = 0; it < NITER; ++it) {
        const int i = tid + it * 256;
        if (i < NCHUNK) {
            const int r  = i / NC4;
            const int c4 = i - r * NC4;
            bf16x4 b = { f2b(G[it].x), f2b(G[it].y), f2b(G[it].z), f2b(G[it].w) };
            *reinterpret_cast<bf16x4*>(&tb[r * TSTRIDE + c4 * 4]) = b;
        }
    }
}

// ---- per-tile MFMA compute (verified rounds 11/12 — unchanged math) ----
// out[oy0+i][ox0+j] = sum_kh sum_k A_kh[i][k]*B_kh[k][j],
// A_kh[i][k] = X[oy0+kh+i][ox0+k], B_kh[k][j] = w[kh][k-j] (banded).
// Consistent k-permutations between A and B cancel; relies only on
// A row = lane&15, B col = lane&15, C/D col=lane&15,row=(lane>>4)*4+reg.
__device__ __forceinline__ void compute_tile(const short* __restrict__ tb,
                                             const short* __restrict__ bmat,
                                             float bv, float* __restrict__ out,
                                             int gx0, int gy0,
                                             int wv, int g, int li) {
    f32x4 acc[4] = {};
    const short* ap = &tb[(16 * wv + li) * TSTRIDE + g * 8];
    const short* bp = &bmat[li * 32 + g * 8];

#pragma unroll 1
    for (int kh = 0; kh < KH; ++kh) {
        const bf16x8 bfrag = *reinterpret_cast<const bf16x8*>(bp + kh * 512);
#pragma unroll
        for (int c = 0; c < 4; ++c) {
            bf16x4 lo = *reinterpret_cast<const bf16x4*>(ap + c * 16);
            bf16x4 hi = *reinterpret_cast<const bf16x4*>(ap + c * 16 + 4);
            bf16x8 a  = __builtin_shufflevector(lo, hi, 0, 1, 2, 3, 4, 5, 6, 7);
            acc[c] = __builtin_amdgcn_mfma_f32_16x16x32_bf16(a, bfrag, acc[c],
                                                             0, 0, 0);
        }
        ap += TSTRIDE;
    }

#pragma unroll
    for (int c = 0; c < 4; ++c) {
        const int ox = gx0 + c * 16 + li;
        if (ox < OW) {
#pragma unroll
            for (int r = 0; r < 4; ++r) {
                const int oy = gy0 + wv * 16 + g * 4 + r;
                if (oy < OH) {
                    out[(size_t)oy * OW + ox] = acc[c][r] + bv;
                }
            }
        }
    }
}

// Persistent 4-tile chain with double-buffered input tile:
//   stage_load(t+1) -> compute(buf[t&1]) -> stage_write(buf[t^1]) -> barrier
// One barrier per tile; buf[t^1] is provably idle (its readers finished
// before the previous barrier). B-fill amortized over 4 tiles.
__global__ __launch_bounds__(256)
void conv2d_mfma4(const float* __restrict__ x,
                  const float* __restrict__ w,
                  const float* __restrict__ bias,
                  float* __restrict__ out) {
    __shared__ short buf[2][TILE_SHORTS];   // 2 x 12432 B
    __shared__ short bmat[KH * 512];        // 11264 B  (total 36128 B)

    const int tid = threadIdx.x;
    // XCD-bijective swizzle (1024 % 8 == 0): each XCD gets 128 contiguous
    // blocks = 8 full tile rows -> x/y halo re-reads hit the same L2.
    const int blk = (blockIdx.x & 7) * (NBLK / 8) + (blockIdx.x >> 3);
    const int t0  = blk * 4;                 // 4 adjacent-x tiles, same row
    const int gy0 = (t0 >> 6) * BM;
    const int gxb = (t0 & (TILES_X - 1)) * BN;

    const int lane = tid & 63;
    const int wv   = tid >> 6;
    const int g    = lane >> 4;
    const int li   = lane & 15;
    const float bv = bias[0];

    // Prologue: stage tile 0 + build B matrices.
    {
        float4 G0[NITER];
        stage_load(G0, x, gxb, gy0, tid);
        stage_write(buf[0], G0, tid);
    }
#pragma unroll
    for (int t = 0; t < 22; ++t) {             // 22*256 = 5632 exact
        const int idx = tid + t * 256;
        const int kh = idx >> 9;
        const int j  = (idx >> 5) & 15;
        const int k  = idx & 31;
        const int d  = k - j;
        const float val = (d >= 0 && d < KW) ? w[kh * KW + d] : 0.f;
        bmat[idx] = f2b(val);
    }
    __syncthreads();

    float4 G[NITER];
#pragma unroll 1
    for (int t = 0; t < 4; ++t) {
        if (t < 3) {
            stage_load(G, x, gxb + (t + 1) * BN, gy0, tid);
            __builtin_amdgcn_sched_barrier(0);   // keep loads above compute
        }
        compute_tile(buf[t & 1], bmat, bv, out, gxb + t * BN, gy0, wv, g, li);
        if (t < 3) {
            stage_write(buf[(t + 1) & 1], G, tid);
            __syncthreads();                     // publish tile t+1
        }
    }
}

extern "C" void kernel_launch(void* const* d_in, const int* in_sizes, int n_in,
                              void* d_out, int out_size, void* d_ws, size_t ws_size,
                              hipStream_t stream) {
    const float* x    = (const float*)d_in[0];
    const float* w    = (const float*)d_in[1];
    const float* bias = (const float*)d_in[2];
    float* out        = (float*)d_out;

    dim3 grid(NBLK);      // 1024 blocks x 4 tiles
    dim3 block(256);
    conv2d_mfma4<<<grid, block, 0, stream>>>(x, w, bias, out);
}